// Round 1
// baseline (7366.512 us; speedup 1.0000x reference)
//
#include <hip/hip_runtime.h>
#include <hip/hip_bf16.h>

// ---------------------------------------------------------------------------
// BiLSTMDecoderModel: V=100000 E=300 H=512 NCLS=6 B=128 S=256
// Key algorithmic facts:
//  * backward LSTM contributes only b_hs[0] = ONE step on seq_emb[0] from 0-state
//    (b_Whh is unused: h=0).
//  * decoder input projection gi[c] = d_Wih @ tanh(ecW[classes[c]]) + d_bih is
//    batch-invariant -> precompute [6][3072].
//  * forward LSTM = 256 sequential steps: persistent kernel, 8 groups x 32 WGs,
//    weights in VGPRs, group-scoped atomic barrier, ping-pong h buffers.
// ---------------------------------------------------------------------------

typedef unsigned short ush;
typedef __bf16 bf16x8 __attribute__((ext_vector_type(8)));
typedef float  f32x4  __attribute__((ext_vector_type(4)));
typedef unsigned short us8 __attribute__((ext_vector_type(8)));

__device__ __forceinline__ ush f2b(float f) {
    __hip_bfloat16 h = __float2bfloat16(f);
    return __builtin_bit_cast(ush, h);
}
__device__ __forceinline__ float b2f(ush u) {
    return __bfloat162float(__builtin_bit_cast(__hip_bfloat16, u));
}
__device__ __forceinline__ float sigm(float x) { return 1.0f / (1.0f + expf(-x)); }

__device__ __forceinline__ bf16x8 ldf(const ush* p) {
    return __builtin_bit_cast(bf16x8, *(const us8*)p);
}
__device__ __forceinline__ f32x4 mfma16(bf16x8 a, bf16x8 b, f32x4 c) {
    // D[m][n] += sum_k A[m][k]*B[k][n]; A frag: m=lane&15, k=(lane>>4)*8+j
    // B frag: n=lane&15, k=(lane>>4)*8+j; D: n=lane&15, m=(lane>>4)*4+reg
    return __builtin_amdgcn_mfma_f32_16x16x32_bf16(a, b, c, 0, 0, 0);
}

// ---- sizes / ws layout (bytes) --------------------------------------------
#define NB   128
#define NS   256
#define NE   300
#define EP   320          // E padded to mult of 32 (zero-filled)
#define EPL  328          // LDS/row stride for E (41*8 -> odd 16B-quads, no conflicts)
#define NH   512
#define HPL  520          // row stride for K=512 (65*8)
#define DH   1024
#define DHL  1032         // row stride for K=1024 (129*8)

static const size_t OFF_SEQ  = 0;              // seq_emb  [256][128][320] ush = 20971520
static const size_t OFF_WIH  = 20971520;       // Wih_r    [2048][328] ush    = 1343488
static const size_t OFF_WHH  = 22315008;       // Whh_r    [2048][520] ush    = 2129920
static const size_t OFF_BWT  = 24444928;       // bWihT    [320][2048] ush    = 1310720
static const size_t OFF_DWHH = 25755648;       // dWhh_r   [3072][1032] ush   = 6340608
static const size_t OFF_GI   = 32096256;       // gi       [6][3072] f32      = 73728
static const size_t OFF_HP   = 32169984;       // h ping   [2][128][512] ush  = 262144
static const size_t OFF_CNT  = 32432128;       // counters [8][32] uint       = 1024
static const size_t OFF_BG   = 32433152;       // bgates   [128][2048] f32    = 1048576
static const size_t OFF_HDEC = 33481728;       // h_dec    [2][128][1024] ush = 524288
// total = 34006016 bytes (~32.4 MiB)

// ---- embedding gather + tanh -> bf16, padded to EP -------------------------
__global__ __launch_bounds__(64) void embed_k(const int* __restrict__ seq,
                                              const float* __restrict__ embW,
                                              ush* __restrict__ seq_emb) {
    int t = blockIdx.x & 255, b = blockIdx.x >> 8;
    int tok = seq[b * NS + t];
    const float* src = embW + (size_t)tok * NE;
    ush* dst = seq_emb + ((size_t)t * NB + b) * EP;
    for (int e = threadIdx.x; e < EP; e += 64)
        dst[e] = (e < NE) ? f2b(tanhf(src[e])) : (ush)0;
}

// ---- weight conversions ----------------------------------------------------
// f_Wih [gate*512+j][300] -> slab order R = w*64 + gate*16 + jl, K padded 328
__global__ __launch_bounds__(128) void conv_wih(const float* __restrict__ W, ush* __restrict__ out) {
    int R = blockIdx.x, w = R >> 6, v = (R >> 4) & 3, jl = R & 15;
    int src = v * NH + w * 16 + jl;
    for (int k = threadIdx.x; k < EPL; k += 128)
        out[(size_t)R * EPL + k] = (k < NE) ? f2b(W[(size_t)src * NE + k]) : (ush)0;
}
__global__ __launch_bounds__(128) void conv_whh(const float* __restrict__ W, ush* __restrict__ out) {
    int R = blockIdx.x, w = R >> 6, v = (R >> 4) & 3, jl = R & 15;
    int src = v * NH + w * 16 + jl;
    for (int k = threadIdx.x; k < HPL; k += 128)
        out[(size_t)R * HPL + k] = (k < NH) ? f2b(W[(size_t)src * NH + k]) : (ush)0;
}
// b_Wih [2048][300] -> transposed [320][2048]
__global__ __launch_bounds__(256) void conv_bwihT(const float* __restrict__ W, ush* __restrict__ out) {
    int k = blockIdx.x;
    for (int r = threadIdx.x; r < 2048; r += 256)
        out[(size_t)k * 2048 + r] = (k < NE) ? f2b(W[(size_t)r * NE + k]) : (ush)0;
}
// d_Whh [3072][1024] -> pad K to 1032 (row order unchanged: row gate*1024+j)
__global__ __launch_bounds__(128) void conv_dwhh(const float* __restrict__ W, ush* __restrict__ out) {
    int R = blockIdx.x;
    for (int k = threadIdx.x; k < DHL; k += 128)
        out[(size_t)R * DHL + k] = (k < DH) ? f2b(W[(size_t)R * DH + k]) : (ush)0;
}

// ---- decoder class-input projection gi[c] = d_Wih @ tanh(ecW[cls]) + d_bih -
__global__ __launch_bounds__(256) void gi_k(const int* __restrict__ classes,
                                            const float* __restrict__ ecW,
                                            const float* __restrict__ dWih,
                                            const float* __restrict__ dbih,
                                            float* __restrict__ gi) {
    __shared__ float ce[NH];
    int c = blockIdx.x / 12, chunk = blockIdx.x % 12;
    int cls = classes[c];
    for (int i = threadIdx.x; i < NH; i += 256) ce[i] = tanhf(ecW[(size_t)cls * NH + i]);
    __syncthreads();
    int r = chunk * 256 + threadIdx.x;
    float acc = dbih[r];
    for (int k = 0; k < NH; ++k) acc += dWih[(size_t)r * NH + k] * ce[k];
    gi[c * 3072 + r] = acc;
}

// ---- backward-LSTM single step (h0 second half) ----------------------------
__global__ __launch_bounds__(256) void bgate_k(const ush* __restrict__ seq_emb,
                                               const ush* __restrict__ bWihT,
                                               const float* __restrict__ bb,
                                               float* __restrict__ bg) {
    int b = blockIdx.y, r = blockIdx.x * 256 + threadIdx.x;
    const ush* x0 = seq_emb + (size_t)b * EP;   // t=0 row for batch b
    float acc = bb[r];
    for (int k = 0; k < NE; ++k) acc += b2f(x0[k]) * b2f(bWihT[(size_t)k * 2048 + r]);
    bg[(size_t)b * 2048 + r] = acc;
}
__global__ __launch_bounds__(256) void bpoint_k(const float* __restrict__ bg,
                                                ush* __restrict__ h_dec0) {
    int idx = blockIdx.x * 256 + threadIdx.x;   // 128*512
    int b = idx >> 9, j = idx & 511;
    const float* g = bg + (size_t)b * 2048;
    float c_ = sigm(g[j]) * tanhf(g[1024 + j]);      // c0 = 0 -> sigm(f)*c0 drops
    float h_ = sigm(g[1536 + j]) * tanhf(c_);
    h_dec0[(size_t)b * DH + NH + j] = f2b(h_);
}

// ---- persistent forward LSTM ----------------------------------------------
// grid 256: group g = bid>>5 (16 batch rows), WG w = bid&31 (h-dims w*16..+16).
// 4 waves = the 4 gates (i,f,g,o). Weight row-slices live in VGPRs.
__global__ __launch_bounds__(256, 2) void lstm_pers(const ush* __restrict__ seq_emb,
                                                    const ush* __restrict__ Wih_r,
                                                    const ush* __restrict__ Whh_r,
                                                    const float* __restrict__ fb,
                                                    ush* __restrict__ h_ping,
                                                    ush* __restrict__ h_dec0,
                                                    unsigned* __restrict__ cnt) {
    __shared__ ush x_lds[16 * EPL];
    __shared__ ush h_lds[16 * HPL];
    __shared__ float gates[16 * 64];   // [m][gate*16+jl]
    __shared__ float c_st[256];        // [m*16+jl]

    const int tid = threadIdx.x;
    const int lane = tid & 63, v = tid >> 6;
    const int l15 = lane & 15, l4 = lane >> 4;
    const int g = blockIdx.x >> 5, w = blockIdx.x & 31;

    // one-time: weight fragments into VGPRs (26 frags = 104 VGPRs)
    bf16x8 wf[10], hf[16];
    {
        const ush* wp = Wih_r + (size_t)((w * 4 + v) * 16 + l15) * EPL + l4 * 8;
#pragma unroll
        for (int ks = 0; ks < 10; ++ks) wf[ks] = ldf(wp + ks * 32);
        const ush* hp = Whh_r + (size_t)((w * 4 + v) * 16 + l15) * HPL + l4 * 8;
#pragma unroll
        for (int ks = 0; ks < 16; ++ks) hf[ks] = ldf(hp + ks * 32);
    }
    const float bias = fb[v * NH + w * 16 + l15];
    c_st[tid] = 0.0f;
    unsigned* mycnt = cnt + g * 32;    // 128B-separated per-group counter

    for (int t = 0; t < NS; ++t) {
        const ush* hsrc = h_ping + (size_t)(t & 1) * NB * NH;
        ush* hdst = h_ping + (size_t)((t + 1) & 1) * NB * NH;
        // stage x[t] (16 rows x 320) and h (16 rows x 512) into LDS
        for (int i = tid; i < 640; i += 256) {
            int r = i / 40, c = i - r * 40;
            *(us8*)&x_lds[r * EPL + c * 8] =
                *(const us8*)&seq_emb[((size_t)t * NB + g * 16 + r) * EP + c * 8];
        }
        for (int i = tid; i < 1024; i += 256) {
            int r = i >> 6, c = i & 63;
            *(us8*)&h_lds[r * HPL + c * 8] =
                *(const us8*)&hsrc[(size_t)(g * 16 + r) * NH + c * 8];
        }
        __syncthreads();

        f32x4 acc = {bias, bias, bias, bias};
#pragma unroll
        for (int ks = 0; ks < 10; ++ks)
            acc = mfma16(ldf(&x_lds[l15 * EPL + ks * 32 + l4 * 8]), wf[ks], acc);
#pragma unroll
        for (int ks = 0; ks < 16; ++ks)
            acc = mfma16(ldf(&h_lds[l15 * HPL + ks * 32 + l4 * 8]), hf[ks], acc);
#pragma unroll
        for (int r0 = 0; r0 < 4; ++r0)
            gates[(l4 * 4 + r0) * 64 + v * 16 + l15] = acc[r0];
        __syncthreads();

        {   // gating: thread = (batch bl, dim jl); c stays WG-local
            const int bl = tid >> 4, jl = tid & 15;
            float gi_ = gates[bl * 64 + jl];
            float gf_ = gates[bl * 64 + 16 + jl];
            float gg_ = gates[bl * 64 + 32 + jl];
            float go_ = gates[bl * 64 + 48 + jl];
            float c_ = sigm(gf_) * c_st[tid] + sigm(gi_) * tanhf(gg_);
            float h_ = sigm(go_) * tanhf(c_);
            c_st[tid] = c_;
            ush hb = f2b(h_);
            hdst[(size_t)(g * 16 + bl) * NH + w * 16 + jl] = hb;
            if (t == NS - 1) h_dec0[(size_t)(g * 16 + bl) * DH + w * 16 + jl] = hb;
        }
        // group barrier: release h slice, wait for all 32 WGs of this group
        __threadfence();
        __syncthreads();
        if (tid == 0) {
            __hip_atomic_fetch_add(mycnt, 1u, __ATOMIC_RELEASE, __HIP_MEMORY_SCOPE_AGENT);
            unsigned tgt = 32u * (unsigned)(t + 1);
            while (__hip_atomic_load(mycnt, __ATOMIC_ACQUIRE, __HIP_MEMORY_SCOPE_AGENT) < tgt)
                __builtin_amdgcn_s_sleep(2);
        }
        __syncthreads();
    }
}

// ---- decoder GRU step ------------------------------------------------------
// grid (8,16): 16 batch x 64 dims per WG; wave v owns dims v*16..+16 and its
// r/z/n rows; gating is per-lane (all three gates in the same lane/reg).
__global__ __launch_bounds__(256) void gru_step(const ush* __restrict__ h_in,
                                                ush* __restrict__ h_out,
                                                const ush* __restrict__ dWhh_r,
                                                const float* __restrict__ gi,
                                                const float* __restrict__ dbhh) {
    __shared__ ush h_lds[16 * DHL];
    const int tid = threadIdx.x, lane = tid & 63, v = tid >> 6;
    const int l15 = lane & 15, l4 = lane >> 4;
    const int bB = blockIdx.x * 16, jB = blockIdx.y * 64;

    for (int i = tid; i < 2048; i += 256) {      // 16 rows x 128 chunks of 8
        int r = i >> 7, c = i & 127;
        *(us8*)&h_lds[r * DHL + c * 8] = *(const us8*)&h_in[(size_t)(bB + r) * DH + c * 8];
    }
    __syncthreads();

    const int jg = jB + v * 16 + l15;
    float b0 = dbhh[jg], b1 = dbhh[DH + jg], b2 = dbhh[2 * DH + jg];
    f32x4 aR = {b0, b0, b0, b0}, aZ = {b1, b1, b1, b1}, aN = {b2, b2, b2, b2};
    const ush* pR = dWhh_r + (size_t)(0 * DH + jg) * DHL + l4 * 8;
    const ush* pZ = dWhh_r + (size_t)(1 * DH + jg) * DHL + l4 * 8;
    const ush* pN = dWhh_r + (size_t)(2 * DH + jg) * DHL + l4 * 8;
#pragma unroll
    for (int ks = 0; ks < 32; ++ks) {
        bf16x8 a = ldf(&h_lds[l15 * DHL + ks * 32 + l4 * 8]);
        aR = mfma16(a, ldf(pR + ks * 32), aR);
        aZ = mfma16(a, ldf(pZ + ks * 32), aZ);
        aN = mfma16(a, ldf(pN + ks * 32), aN);
    }
    const float giR = gi[jg], giZ = gi[DH + jg], giN = gi[2 * DH + jg];
#pragma unroll
    for (int r0 = 0; r0 < 4; ++r0) {
        int m = l4 * 4 + r0;
        float r_ = sigm(giR + aR[r0]);
        float z_ = sigm(giZ + aZ[r0]);
        float n_ = tanhf(giN + r_ * aN[r0]);
        float hold = b2f(h_lds[m * DHL + jg]);
        float ho = tanhf((1.0f - z_) * n_ + z_ * hold);
        h_out[(size_t)(bB + m) * DH + jg] = f2b(ho);
    }
}

// ---- logits + log_softmax(2) ----------------------------------------------
__global__ __launch_bounds__(64) void logits_k(const ush* __restrict__ h,
                                               const float* __restrict__ clsW,
                                               const float* __restrict__ clsb,
                                               float* __restrict__ out) {
    int b = blockIdx.x, lane = threadIdx.x;
    float s0 = 0.f, s1 = 0.f;
    for (int k = lane; k < DH; k += 64) {
        float hv = b2f(h[(size_t)b * DH + k]);
        s0 += hv * clsW[k];
        s1 += hv * clsW[DH + k];
    }
    for (int off = 32; off; off >>= 1) {
        s0 += __shfl_down(s0, off, 64);
        s1 += __shfl_down(s1, off, 64);
    }
    if (lane == 0) {
        float l0 = s0 + clsb[0], l1 = s1 + clsb[1];
        float m = fmaxf(l0, l1);
        float d = logf(expf(l0 - m) + expf(l1 - m));
        out[b * 2 + 0] = l0 - m - d;
        out[b * 2 + 1] = l1 - m - d;
    }
}

// ---------------------------------------------------------------------------
extern "C" void kernel_launch(void* const* d_in, const int* in_sizes, int n_in,
                              void* d_out, int out_size, void* d_ws, size_t ws_size,
                              hipStream_t stream) {
    (void)in_sizes; (void)n_in; (void)out_size; (void)ws_size;
    const int*   seq  = (const int*)  d_in[0];
    const int*   cls  = (const int*)  d_in[1];
    const float* embW = (const float*)d_in[2];
    const float* ecW  = (const float*)d_in[3];
    const float* fWih = (const float*)d_in[4];
    const float* fWhh = (const float*)d_in[5];
    const float* fb   = (const float*)d_in[6];
    const float* bWih = (const float*)d_in[7];
    /* d_in[8] = b_Whh is provably unused (h0 = 0) */
    const float* bb   = (const float*)d_in[9];
    const float* dWih = (const float*)d_in[10];
    const float* dWhh = (const float*)d_in[11];
    const float* dbih = (const float*)d_in[12];
    const float* dbhh = (const float*)d_in[13];
    const float* clsW = (const float*)d_in[14];
    const float* clsb = (const float*)d_in[15];
    float* outF = (float*)d_out;

    char* ws = (char*)d_ws;
    ush*      seq_emb = (ush*)(ws + OFF_SEQ);
    ush*      Wih_r   = (ush*)(ws + OFF_WIH);
    ush*      Whh_r   = (ush*)(ws + OFF_WHH);
    ush*      bWihT   = (ush*)(ws + OFF_BWT);
    ush*      dWhh_r  = (ush*)(ws + OFF_DWHH);
    float*    gi      = (float*)(ws + OFF_GI);
    ush*      h_ping  = (ush*)(ws + OFF_HP);
    unsigned* cnt     = (unsigned*)(ws + OFF_CNT);
    float*    bg      = (float*)(ws + OFF_BG);
    ush*      h_dec   = (ush*)(ws + OFF_HDEC);

    // zero initial hidden state (both ping-pong halves) + barrier counters
    hipMemsetAsync(ws + OFF_HP, 0, (size_t)(2 * NB * NH * 2 + 1024), stream);

    embed_k<<<NB * NS, 64, 0, stream>>>(seq, embW, seq_emb);
    conv_wih<<<2048, 128, 0, stream>>>(fWih, Wih_r);
    conv_whh<<<2048, 128, 0, stream>>>(fWhh, Whh_r);
    conv_bwihT<<<EP, 256, 0, stream>>>(bWih, bWihT);
    conv_dwhh<<<3072, 128, 0, stream>>>(dWhh, dWhh_r);
    gi_k<<<72, 256, 0, stream>>>(cls, ecW, dWih, dbih, gi);
    bgate_k<<<dim3(8, NB), 256, 0, stream>>>(seq_emb, bWihT, bb, bg);
    bpoint_k<<<256, 256, 0, stream>>>(bg, h_dec);   // writes h_dec[0][:, 512:]

    lstm_pers<<<256, 256, 0, stream>>>(seq_emb, Wih_r, Whh_r, fb, h_ping, h_dec, cnt);

    for (int c = 0; c < 6; ++c) {
        const ush* hin = h_dec + (size_t)(c & 1) * NB * DH;
        ush* hout      = h_dec + (size_t)((c + 1) & 1) * NB * DH;
        gru_step<<<dim3(8, 16), 256, 0, stream>>>(hin, hout, dWhh_r, gi + c * 3072, dbhh);
        logits_k<<<NB, 64, 0, stream>>>(hout, clsW, clsb, outF + c * NB * 2);
    }
}

// Round 2
// 1996.851 us; speedup vs baseline: 3.6891x; 3.6891x over previous
//
#include <hip/hip_runtime.h>
#include <hip/hip_bf16.h>

// ---------------------------------------------------------------------------
// BiLSTMDecoderModel: V=100000 E=300 H=512 NCLS=6 B=128 S=256
//  * backward LSTM contributes only b_hs[0] = ONE step on seq_emb[0] (h0=0,
//    b_Whh unused).
//  * decoder input projection gi[c] is batch-invariant -> precompute [6][3072].
//  * forward LSTM: persistent kernel, 8 groups x 32 WGs, weights pinned in
//    VGPRs, fence-free group barrier (relaxed agent atomics + vmcnt ordering).
//    Round-1 lesson: agent acquire/release fences emit buffer_wbl2/buffer_inv
//    -> L2 flushed every step -> 27us/step. This version has NO cache fences.
// ---------------------------------------------------------------------------

typedef unsigned short ush;
typedef __bf16 bf16x8 __attribute__((ext_vector_type(8)));
typedef float  f32x4  __attribute__((ext_vector_type(4)));
typedef unsigned short us8 __attribute__((ext_vector_type(8)));

__device__ __forceinline__ ush f2b(float f) {
    __hip_bfloat16 h = __float2bfloat16(f);
    return __builtin_bit_cast(ush, h);
}
__device__ __forceinline__ float b2f(ush u) {
    return __bfloat162float(__builtin_bit_cast(__hip_bfloat16, u));
}
__device__ __forceinline__ float sigm(float x) { return 1.0f / (1.0f + expf(-x)); }

__device__ __forceinline__ bf16x8 ldf(const ush* p) {
    return __builtin_bit_cast(bf16x8, *(const us8*)p);
}
__device__ __forceinline__ f32x4 mfma16(bf16x8 a, bf16x8 b, f32x4 c) {
    // D[m][n] += sum_k A[m][k]*B[k][n]; A: m=lane&15,k=(lane>>4)*8+j
    // B: n=lane&15,k=(lane>>4)*8+j; D: n=lane&15, m=(lane>>4)*4+reg
    return __builtin_amdgcn_mfma_f32_16x16x32_bf16(a, b, c, 0, 0, 0);
}

// ---- sizes / ws layout (bytes) --------------------------------------------
#define NB   128
#define NS   256
#define NE   300
#define EP   320
#define EPL  328
#define NH   512
#define HPL  520
#define DH   1024
#define DHL  1032

static const size_t OFF_SEQ  = 0;              // seq_emb  [256][128][320] ush
static const size_t OFF_WIH  = 20971520;       // Wih_r    [2048][328] ush
static const size_t OFF_WHH  = 22315008;       // Whh_r    [2048][520] ush
static const size_t OFF_BWT  = 24444928;       // bWihT    [320][2048] ush
static const size_t OFF_DWHH = 25755648;       // dWhh_r   [3072][1032] ush
static const size_t OFF_GI   = 32096256;       // gi       [6][3072] f32
static const size_t OFF_HP   = 32169984;       // h ping   [2][128][512] ush
static const size_t OFF_CNT  = 32432128;       // counters [8][32] uint
static const size_t OFF_BG   = 32433152;       // bgates   [128][2048] f32
static const size_t OFF_HDEC = 33481728;       // h_dec    [2][128][1024] ush
// total = 34006016 bytes (~32.4 MiB)

// ---- embedding gather + tanh -> bf16, padded to EP -------------------------
__global__ __launch_bounds__(64) void embed_k(const int* __restrict__ seq,
                                              const float* __restrict__ embW,
                                              ush* __restrict__ seq_emb) {
    int t = blockIdx.x & 255, b = blockIdx.x >> 8;
    int tok = seq[b * NS + t];
    const float* src = embW + (size_t)tok * NE;
    ush* dst = seq_emb + ((size_t)t * NB + b) * EP;
    for (int e = threadIdx.x; e < EP; e += 64)
        dst[e] = (e < NE) ? f2b(tanhf(src[e])) : (ush)0;
}

// ---- weight conversions ----------------------------------------------------
__global__ __launch_bounds__(128) void conv_wih(const float* __restrict__ W, ush* __restrict__ out) {
    int R = blockIdx.x, w = R >> 6, v = (R >> 4) & 3, jl = R & 15;
    int src = v * NH + w * 16 + jl;
    for (int k = threadIdx.x; k < EPL; k += 128)
        out[(size_t)R * EPL + k] = (k < NE) ? f2b(W[(size_t)src * NE + k]) : (ush)0;
}
__global__ __launch_bounds__(128) void conv_whh(const float* __restrict__ W, ush* __restrict__ out) {
    int R = blockIdx.x, w = R >> 6, v = (R >> 4) & 3, jl = R & 15;
    int src = v * NH + w * 16 + jl;
    for (int k = threadIdx.x; k < HPL; k += 128)
        out[(size_t)R * HPL + k] = (k < NH) ? f2b(W[(size_t)src * NH + k]) : (ush)0;
}
__global__ __launch_bounds__(256) void conv_bwihT(const float* __restrict__ W, ush* __restrict__ out) {
    int k = blockIdx.x;
    for (int r = threadIdx.x; r < 2048; r += 256)
        out[(size_t)k * 2048 + r] = (k < NE) ? f2b(W[(size_t)r * NE + k]) : (ush)0;
}
__global__ __launch_bounds__(128) void conv_dwhh(const float* __restrict__ W, ush* __restrict__ out) {
    int R = blockIdx.x;
    for (int k = threadIdx.x; k < DHL; k += 128)
        out[(size_t)R * DHL + k] = (k < DH) ? f2b(W[(size_t)R * DH + k]) : (ush)0;
}

// ---- decoder class-input projection ----------------------------------------
__global__ __launch_bounds__(256) void gi_k(const int* __restrict__ classes,
                                            const float* __restrict__ ecW,
                                            const float* __restrict__ dWih,
                                            const float* __restrict__ dbih,
                                            float* __restrict__ gi) {
    __shared__ float ce[NH];
    int c = blockIdx.x / 12, chunk = blockIdx.x % 12;
    int cls = classes[c];
    for (int i = threadIdx.x; i < NH; i += 256) ce[i] = tanhf(ecW[(size_t)cls * NH + i]);
    __syncthreads();
    int r = chunk * 256 + threadIdx.x;
    float acc = dbih[r];
    for (int k = 0; k < NH; ++k) acc += dWih[(size_t)r * NH + k] * ce[k];
    gi[c * 3072 + r] = acc;
}

// ---- backward-LSTM single step (h0 second half) ----------------------------
__global__ __launch_bounds__(256) void bgate_k(const ush* __restrict__ seq_emb,
                                               const ush* __restrict__ bWihT,
                                               const float* __restrict__ bb,
                                               float* __restrict__ bg) {
    int b = blockIdx.y, r = blockIdx.x * 256 + threadIdx.x;
    const ush* x0 = seq_emb + (size_t)b * EP;
    float acc = bb[r];
    for (int k = 0; k < NE; ++k) acc += b2f(x0[k]) * b2f(bWihT[(size_t)k * 2048 + r]);
    bg[(size_t)b * 2048 + r] = acc;
}
__global__ __launch_bounds__(256) void bpoint_k(const float* __restrict__ bg,
                                                ush* __restrict__ h_dec0) {
    int idx = blockIdx.x * 256 + threadIdx.x;
    int b = idx >> 9, j = idx & 511;
    const float* g = bg + (size_t)b * 2048;
    float c_ = sigm(g[j]) * tanhf(g[1024 + j]);
    float h_ = sigm(g[1536 + j]) * tanhf(c_);
    h_dec0[(size_t)b * DH + NH + j] = f2b(h_);
}

// ---- persistent forward LSTM (fence-free barrier) --------------------------
// grid 256: group g = bid>>5 (16 batch rows), WG w = bid&31 (h-dims w*16..+16).
// 4 waves = 4 gates. Weight slices pinned in VGPRs via opaque asm.
// Barrier: h exchanged via RELAXED agent atomics (sc0/sc1 UC ops, coherent at
// MALL, no L2 flush); per-wave s_waitcnt vmcnt(0) + lane0 relaxed atomicAdd;
// tid0 spins on counter. 3 __syncthreads per step.
__global__ __launch_bounds__(256, 1) void lstm_pers(const ush* __restrict__ seq_emb,
                                                    const ush* __restrict__ Wih_r,
                                                    const ush* __restrict__ Whh_r,
                                                    const float* __restrict__ fb,
                                                    ush* __restrict__ h_ping,
                                                    ush* __restrict__ h_dec0,
                                                    unsigned* __restrict__ cnt) {
    __shared__ ush x_lds[2][16 * EPL];
    __shared__ ush h_lds[16 * HPL];
    __shared__ float gates[16 * 64];   // [m][gate*16+jl]

    const int tid = threadIdx.x;
    const int lane = tid & 63, v = tid >> 6;
    const int l15 = lane & 15, l4 = lane >> 4;
    const int g = blockIdx.x >> 5, w = blockIdx.x & 31;
    const int bl = tid >> 4, jl = tid & 15;

    // one-time: weight fragments into VGPRs, pinned with opaque asm
    bf16x8 wf[10], hf[16];
    {
        const ush* wp = Wih_r + (size_t)((w * 4 + v) * 16 + l15) * EPL + l4 * 8;
#pragma unroll
        for (int ks = 0; ks < 10; ++ks) wf[ks] = ldf(wp + ks * 32);
        const ush* hp = Whh_r + (size_t)((w * 4 + v) * 16 + l15) * HPL + l4 * 8;
#pragma unroll
        for (int ks = 0; ks < 16; ++ks) hf[ks] = ldf(hp + ks * 32);
    }
#pragma unroll
    for (int ks = 0; ks < 10; ++ks) {
        f32x4 tmp = __builtin_bit_cast(f32x4, wf[ks]);
        asm volatile("" : "+v"(tmp));
        wf[ks] = __builtin_bit_cast(bf16x8, tmp);
    }
#pragma unroll
    for (int ks = 0; ks < 16; ++ks) {
        f32x4 tmp = __builtin_bit_cast(f32x4, hf[ks]);
        asm volatile("" : "+v"(tmp));
        hf[ks] = __builtin_bit_cast(bf16x8, tmp);
    }

    const float bias = fb[v * NH + w * 16 + l15];
    float c_reg = 0.0f;                       // cell state for (bl, jl)
    unsigned* mycnt = cnt + g * 32;

    // prologue: stage x[0]; h(0) = 0 directly in LDS
    for (int i = tid; i < 640; i += 256) {
        int r = i / 40, c = i - r * 40;
        *(us8*)&x_lds[0][r * EPL + c * 8] =
            *(const us8*)&seq_emb[((size_t)(g * 16 + r)) * EP + c * 8];
    }
    for (int i = tid; i < 2080; i += 256)
        ((unsigned long long*)h_lds)[i] = 0ull;
    __syncthreads();

    for (int t = 0; t < NS; ++t) {
        // A: gates = x@WihT + h@WhhT + b
        f32x4 acc = {bias, bias, bias, bias};
        const ush* xb = &x_lds[t & 1][l15 * EPL + l4 * 8];
#pragma unroll
        for (int ks = 0; ks < 10; ++ks)
            acc = mfma16(ldf(xb + ks * 32), wf[ks], acc);
#pragma unroll
        for (int ks = 0; ks < 16; ++ks)
            acc = mfma16(ldf(&h_lds[l15 * HPL + ks * 32 + l4 * 8]), hf[ks], acc);
#pragma unroll
        for (int r0 = 0; r0 < 4; ++r0)
            gates[(l4 * 4 + r0) * 64 + v * 16 + l15] = acc[r0];
        __syncthreads();                                  // sync1

        // stage x[t+1] into other buffer (overlaps barrier latency)
        if (t + 1 < NS) {
            for (int i = tid; i < 640; i += 256) {
                int r = i / 40, c = i - r * 40;
                *(us8*)&x_lds[(t + 1) & 1][r * EPL + c * 8] =
                    *(const us8*)&seq_emb[((size_t)(t + 1) * NB + g * 16 + r) * EP + c * 8];
            }
        }

        // B: gating (per-thread c stays in a register)
        float gi_ = gates[bl * 64 + jl];
        float gf_ = gates[bl * 64 + 16 + jl];
        float gg_ = gates[bl * 64 + 32 + jl];
        float go_ = gates[bl * 64 + 48 + jl];
        float c_ = sigm(gf_) * c_reg + sigm(gi_) * tanhf(gg_);
        float h_ = sigm(go_) * tanhf(c_);
        c_reg = c_;
        ush hb = f2b(h_);

        if (t == NS - 1) {
            h_dec0[(size_t)(g * 16 + bl) * DH + w * 16 + jl] = hb;
            break;                                        // uniform branch
        }

        // publish h slice: UC dword stores (pairs of bf16), no cache fences
        unsigned nb = (unsigned)__shfl_down((int)hb, 1, 64);
        if ((jl & 1) == 0) {
            unsigned pair = (unsigned)hb | (nb << 16);
            unsigned* dst = (unsigned*)&h_ping[((size_t)((t + 1) & 1) * NB + g * 16 + bl) * NH + w * 16 + jl];
            __hip_atomic_store(dst, pair, __ATOMIC_RELAXED, __HIP_MEMORY_SCOPE_AGENT);
        }
        asm volatile("s_waitcnt vmcnt(0)" ::: "memory");  // stores acked at MALL
        if (lane == 0)
            __hip_atomic_fetch_add(mycnt, 1u, __ATOMIC_RELAXED, __HIP_MEMORY_SCOPE_AGENT);

        // C: wait for all 128 waves of the group
        if (tid == 0) {
            unsigned tgt = 128u * (unsigned)(t + 1);
            while (__hip_atomic_load(mycnt, __ATOMIC_RELAXED, __HIP_MEMORY_SCOPE_AGENT) < tgt) {}
        }
        __syncthreads();                                  // sync2

        // D: re-stage full group h from MALL (UC u64 loads)
        const ush* hsrc = h_ping + (size_t)((t + 1) & 1) * NB * NH;
        for (int i = tid; i < 1024; i += 256) {
            int r = i >> 6, c = i & 63;
            unsigned long long vz = __hip_atomic_load(
                (const unsigned long long*)(hsrc + (size_t)(g * 16 + r) * NH) + c,
                __ATOMIC_RELAXED, __HIP_MEMORY_SCOPE_AGENT);
            *(unsigned long long*)&h_lds[r * HPL + c * 4] = vz;
        }
        __syncthreads();                                  // sync3
    }
}

// ---- decoder GRU step ------------------------------------------------------
__global__ __launch_bounds__(256) void gru_step(const ush* __restrict__ h_in,
                                                ush* __restrict__ h_out,
                                                const ush* __restrict__ dWhh_r,
                                                const float* __restrict__ gi,
                                                const float* __restrict__ dbhh) {
    __shared__ ush h_lds[16 * DHL];
    const int tid = threadIdx.x, lane = tid & 63, v = tid >> 6;
    const int l15 = lane & 15, l4 = lane >> 4;
    const int bB = blockIdx.x * 16, jB = blockIdx.y * 64;

    for (int i = tid; i < 2048; i += 256) {
        int r = i >> 7, c = i & 127;
        *(us8*)&h_lds[r * DHL + c * 8] = *(const us8*)&h_in[(size_t)(bB + r) * DH + c * 8];
    }
    __syncthreads();

    const int jg = jB + v * 16 + l15;
    float b0 = dbhh[jg], b1 = dbhh[DH + jg], b2 = dbhh[2 * DH + jg];
    f32x4 aR = {b0, b0, b0, b0}, aZ = {b1, b1, b1, b1}, aN = {b2, b2, b2, b2};
    const ush* pR = dWhh_r + (size_t)(0 * DH + jg) * DHL + l4 * 8;
    const ush* pZ = dWhh_r + (size_t)(1 * DH + jg) * DHL + l4 * 8;
    const ush* pN = dWhh_r + (size_t)(2 * DH + jg) * DHL + l4 * 8;
#pragma unroll
    for (int ks = 0; ks < 32; ++ks) {
        bf16x8 a = ldf(&h_lds[l15 * DHL + ks * 32 + l4 * 8]);
        aR = mfma16(a, ldf(pR + ks * 32), aR);
        aZ = mfma16(a, ldf(pZ + ks * 32), aZ);
        aN = mfma16(a, ldf(pN + ks * 32), aN);
    }
    const float giR = gi[jg], giZ = gi[DH + jg], giN = gi[2 * DH + jg];
#pragma unroll
    for (int r0 = 0; r0 < 4; ++r0) {
        int m = l4 * 4 + r0;
        float r_ = sigm(giR + aR[r0]);
        float z_ = sigm(giZ + aZ[r0]);
        float n_ = tanhf(giN + r_ * aN[r0]);
        float hold = b2f(h_lds[m * DHL + jg]);
        float ho = tanhf((1.0f - z_) * n_ + z_ * hold);
        h_out[(size_t)(bB + m) * DH + jg] = f2b(ho);
    }
}

// ---- logits + log_softmax(2) ----------------------------------------------
__global__ __launch_bounds__(64) void logits_k(const ush* __restrict__ h,
                                               const float* __restrict__ clsW,
                                               const float* __restrict__ clsb,
                                               float* __restrict__ out) {
    int b = blockIdx.x, lane = threadIdx.x;
    float s0 = 0.f, s1 = 0.f;
    for (int k = lane; k < DH; k += 64) {
        float hv = b2f(h[(size_t)b * DH + k]);
        s0 += hv * clsW[k];
        s1 += hv * clsW[DH + k];
    }
    for (int off = 32; off; off >>= 1) {
        s0 += __shfl_down(s0, off, 64);
        s1 += __shfl_down(s1, off, 64);
    }
    if (lane == 0) {
        float l0 = s0 + clsb[0], l1 = s1 + clsb[1];
        float m = fmaxf(l0, l1);
        float d = logf(expf(l0 - m) + expf(l1 - m));
        out[b * 2 + 0] = l0 - m - d;
        out[b * 2 + 1] = l1 - m - d;
    }
}

// ---------------------------------------------------------------------------
extern "C" void kernel_launch(void* const* d_in, const int* in_sizes, int n_in,
                              void* d_out, int out_size, void* d_ws, size_t ws_size,
                              hipStream_t stream) {
    (void)in_sizes; (void)n_in; (void)out_size; (void)ws_size;
    const int*   seq  = (const int*)  d_in[0];
    const int*   cls  = (const int*)  d_in[1];
    const float* embW = (const float*)d_in[2];
    const float* ecW  = (const float*)d_in[3];
    const float* fWih = (const float*)d_in[4];
    const float* fWhh = (const float*)d_in[5];
    const float* fb   = (const float*)d_in[6];
    const float* bWih = (const float*)d_in[7];
    /* d_in[8] = b_Whh unused (h0 = 0) */
    const float* bb   = (const float*)d_in[9];
    const float* dWih = (const float*)d_in[10];
    const float* dWhh = (const float*)d_in[11];
    const float* dbih = (const float*)d_in[12];
    const float* dbhh = (const float*)d_in[13];
    const float* clsW = (const float*)d_in[14];
    const float* clsb = (const float*)d_in[15];
    float* outF = (float*)d_out;

    char* ws = (char*)d_ws;
    ush*      seq_emb = (ush*)(ws + OFF_SEQ);
    ush*      Wih_r   = (ush*)(ws + OFF_WIH);
    ush*      Whh_r   = (ush*)(ws + OFF_WHH);
    ush*      bWihT   = (ush*)(ws + OFF_BWT);
    ush*      dWhh_r  = (ush*)(ws + OFF_DWHH);
    float*    gi      = (float*)(ws + OFF_GI);
    ush*      h_ping  = (ush*)(ws + OFF_HP);
    unsigned* cnt     = (unsigned*)(ws + OFF_CNT);
    float*    bg      = (float*)(ws + OFF_BG);
    ush*      h_dec   = (ush*)(ws + OFF_HDEC);

    // zero h ping-pong + barrier counters (graph replays this each run)
    hipMemsetAsync(ws + OFF_HP, 0, (size_t)(2 * NB * NH * 2 + 1024), stream);

    embed_k<<<NB * NS, 64, 0, stream>>>(seq, embW, seq_emb);
    conv_wih<<<2048, 128, 0, stream>>>(fWih, Wih_r);
    conv_whh<<<2048, 128, 0, stream>>>(fWhh, Whh_r);
    conv_bwihT<<<EP, 256, 0, stream>>>(bWih, bWihT);
    conv_dwhh<<<3072, 128, 0, stream>>>(dWhh, dWhh_r);
    gi_k<<<72, 256, 0, stream>>>(cls, ecW, dWih, dbih, gi);
    bgate_k<<<dim3(8, NB), 256, 0, stream>>>(seq_emb, bWihT, bb, bg);
    bpoint_k<<<256, 256, 0, stream>>>(bg, h_dec);

    lstm_pers<<<256, 256, 0, stream>>>(seq_emb, Wih_r, Whh_r, fb, h_ping, h_dec, cnt);

    for (int c = 0; c < 6; ++c) {
        const ush* hin = h_dec + (size_t)(c & 1) * NB * DH;
        ush* hout      = h_dec + (size_t)((c + 1) & 1) * NB * DH;
        gru_step<<<dim3(8, 16), 256, 0, stream>>>(hin, hout, dWhh_r, gi + c * 3072, dbhh);
        logits_k<<<NB, 64, 0, stream>>>(hout, clsW, clsb, outF + c * NB * 2);
    }
}